// Round 1
// baseline (1057.095 us; speedup 1.0000x reference)
//
#include <hip/hip_runtime.h>

typedef __attribute__((ext_vector_type(8))) short short8;
typedef __attribute__((ext_vector_type(4))) float f32x4;

__device__ __forceinline__ short f2bf(float f) {
  unsigned u = __float_as_uint(f);
  u += 0x7fff + ((u >> 16) & 1);   // round-to-nearest-even
  return (short)(u >> 16);
}

__device__ __forceinline__ short8 cvt8(const float* __restrict__ p) {
  float4 a = *(const float4*)p;
  float4 b = *(const float4*)(p + 4);
  short8 s;
  s[0] = f2bf(a.x); s[1] = f2bf(a.y); s[2] = f2bf(a.z); s[3] = f2bf(a.w);
  s[4] = f2bf(b.x); s[5] = f2bf(b.y); s[6] = f2bf(b.z); s[7] = f2bf(b.w);
  return s;
}

// C[m][n] = sum_k A[m][k] * B[n][k]   (A: MxK row-major, B: NxK row-major)
// MODE 0: out bf16 at ((b*16+h)*2048 + l)*64 + d   (m=b*2048+l, n=h*64+d)  [Q/K proj]
// MODE 1: out bf16 at (bz*1024 + m)*2048 + n                               [V proj, transposed]
// MODE 2: out fp32 at m*N + n                                              [final y]
template <int MODE>
__global__ __launch_bounds__(256) void gemm_bt(const float* __restrict__ Aall,
                                               const float* __restrict__ Ball,
                                               void* __restrict__ Cout,
                                               int M, int N, int K,
                                               long aBatch, long bBatch) {
  __shared__ __align__(16) short As[128][72];
  __shared__ __align__(16) short Bs[128][72];
  const int bm = blockIdx.x, bn = blockIdx.y, bz = blockIdx.z;
  const float* A = Aall + (long)bz * aBatch;
  const float* B = Ball + (long)bz * bBatch;
  const int tid = threadIdx.x;
  const int wave = tid >> 6, lane = tid & 63;
  const int quad = lane >> 4, l16 = lane & 15;
  const int wm = (wave >> 1) * 64, wn = (wave & 1) * 64;

  const f32x4 zero = {0.f, 0.f, 0.f, 0.f};
  f32x4 acc[4][4];
  for (int i = 0; i < 4; i++)
    for (int j = 0; j < 4; j++) acc[i][j] = zero;

  for (int kt = 0; kt < K; kt += 64) {
    __syncthreads();
    for (int u = tid; u < 1024; u += 256) {
      int row = u >> 3, ch = u & 7;
      *(short8*)&As[row][ch * 8] = cvt8(A + (long)(bm * 128 + row) * K + kt + ch * 8);
    }
    for (int u = tid; u < 1024; u += 256) {
      int row = u >> 3, ch = u & 7;
      *(short8*)&Bs[row][ch * 8] = cvt8(B + (long)(bn * 128 + row) * K + kt + ch * 8);
    }
    __syncthreads();
    for (int kk = 0; kk < 64; kk += 32) {
      short8 af[4], bfr[4];
      for (int i = 0; i < 4; i++) af[i] = *(const short8*)&As[wm + i * 16 + l16][kk + quad * 8];
      for (int j = 0; j < 4; j++) bfr[j] = *(const short8*)&Bs[wn + j * 16 + l16][kk + quad * 8];
      for (int i = 0; i < 4; i++)
        for (int j = 0; j < 4; j++)
          acc[i][j] = __builtin_amdgcn_mfma_f32_16x16x32_bf16(af[i], bfr[j], acc[i][j], 0, 0, 0);
    }
  }

  for (int i = 0; i < 4; i++)
    for (int j = 0; j < 4; j++)
      for (int r = 0; r < 4; r++) {
        int grow = bm * 128 + wm + i * 16 + quad * 4 + r;
        int gcol = bn * 128 + wn + j * 16 + l16;
        float val = acc[i][j][r];
        if (MODE == 0) {
          int b = grow >> 11, l = grow & 2047, h = gcol >> 6, d = gcol & 63;
          ((short*)Cout)[(((long)(b * 16 + h) * 2048 + l) * 64 + d)] = f2bf(val);
        } else if (MODE == 1) {
          ((short*)Cout)[((long)bz * 1024 + grow) * 2048 + gcol] = f2bf(val);
        } else {
          ((float*)Cout)[(long)grow * N + gcol] = val;
        }
      }
}

// attention: grid (32 qtiles, 16 heads, 2 batch), 256 threads.
// qh,kh: (b,h,l,d) bf16; vht: (b,h,d,l) bf16; attn_out fp32 (b,h,lq,lk); yh fp32 (b,l,h*64+d)
__global__ __launch_bounds__(256) void attn_kernel(const short* __restrict__ qh,
                                                   const short* __restrict__ kh,
                                                   const short* __restrict__ vht,
                                                   float* __restrict__ attn_out,
                                                   float* __restrict__ yh_out) {
  __shared__ __align__(16) short q_s[64][72];
  __shared__ __align__(16) short k_s[64][72];
  __shared__ __align__(16) short v_s[64][72];
  __shared__ __align__(16) short p_s[64][72];
  constexpr float SCALE = 0.022097086912079608f;  // 1/sqrt(2048)

  const int qb = blockIdx.x, h = blockIdx.y, b = blockIdx.z;
  const long bh = b * 16 + h;
  const short* Q = qh + bh * (2048L * 64) + (long)qb * 64 * 64;
  const short* Kp = kh + bh * (2048L * 64);
  const short* Vt = vht + bh * (64L * 2048);
  float* attnp = attn_out + bh * (2048L * 2048) + (long)qb * 64 * 2048;

  const int tid = threadIdx.x;
  const int wave = tid >> 6, lane = tid & 63, quad = lane >> 4, l16 = lane & 15;
  const int myrow0 = wave * 16;
  const f32x4 zero = {0.f, 0.f, 0.f, 0.f};

  for (int u = tid; u < 512; u += 256) {
    int row = u >> 3, ch = u & 7;
    *(short8*)&q_s[row][ch * 8] = *(const short8*)(Q + row * 64 + ch * 8);
  }

  float mrow[4], lrow[4];
  for (int r = 0; r < 4; r++) { mrow[r] = -1e30f; lrow[r] = 0.f; }

  // ---- pass A: online row max + sum(exp) ----
  for (int kt = 0; kt < 32; ++kt) {
    __syncthreads();
    for (int u = tid; u < 512; u += 256) {
      int row = u >> 3, ch = u & 7;
      *(short8*)&k_s[row][ch * 8] = *(const short8*)(Kp + (kt * 64 + row) * 64 + ch * 8);
    }
    __syncthreads();
    short8 a0 = *(const short8*)&q_s[myrow0 + l16][quad * 8];
    short8 a1 = *(const short8*)&q_s[myrow0 + l16][32 + quad * 8];
    f32x4 sc[4];
    for (int nt = 0; nt < 4; ++nt) {
      short8 b0 = *(const short8*)&k_s[nt * 16 + l16][quad * 8];
      short8 b1 = *(const short8*)&k_s[nt * 16 + l16][32 + quad * 8];
      f32x4 c = zero;
      c = __builtin_amdgcn_mfma_f32_16x16x32_bf16(a0, b0, c, 0, 0, 0);
      c = __builtin_amdgcn_mfma_f32_16x16x32_bf16(a1, b1, c, 0, 0, 0);
      sc[nt] = c;
    }
    for (int r = 0; r < 4; ++r) {
      float s0 = sc[0][r] * SCALE, s1 = sc[1][r] * SCALE;
      float s2 = sc[2][r] * SCALE, s3 = sc[3][r] * SCALE;
      float tm = fmaxf(fmaxf(s0, s1), fmaxf(s2, s3));
      float mn = fmaxf(mrow[r], tm);
      lrow[r] = lrow[r] * __expf(mrow[r] - mn) + __expf(s0 - mn) + __expf(s1 - mn) +
                __expf(s2 - mn) + __expf(s3 - mn);
      mrow[r] = mn;
    }
  }
  // combine (m,l) across the 16 lanes sharing a quad group
  for (int r = 0; r < 4; ++r) {
    float m = mrow[r], l = lrow[r];
    for (int off = 1; off < 16; off <<= 1) {
      float mo = __shfl_xor(m, off);
      float lo = __shfl_xor(l, off);
      float mn = fmaxf(m, mo);
      l = l * __expf(m - mn) + lo * __expf(mo - mn);
      m = mn;
    }
    mrow[r] = m;
    lrow[r] = 1.0f / l;
  }

  // ---- pass B: recompute S, write attn, PV ----
  f32x4 oacc[4];
  for (int nt = 0; nt < 4; nt++) oacc[nt] = zero;
  for (int kt = 0; kt < 32; ++kt) {
    __syncthreads();
    for (int u = tid; u < 1024; u += 256) {
      int which = u >> 9, uu = u & 511;
      int row = uu >> 3, ch = uu & 7;
      if (which == 0)
        *(short8*)&k_s[row][ch * 8] = *(const short8*)(Kp + (kt * 64 + row) * 64 + ch * 8);
      else
        *(short8*)&v_s[row][ch * 8] = *(const short8*)(Vt + (long)row * 2048 + kt * 64 + ch * 8);
    }
    __syncthreads();
    short8 a0 = *(const short8*)&q_s[myrow0 + l16][quad * 8];
    short8 a1 = *(const short8*)&q_s[myrow0 + l16][32 + quad * 8];
    for (int nt = 0; nt < 4; ++nt) {
      short8 b0 = *(const short8*)&k_s[nt * 16 + l16][quad * 8];
      short8 b1 = *(const short8*)&k_s[nt * 16 + l16][32 + quad * 8];
      f32x4 c = zero;
      c = __builtin_amdgcn_mfma_f32_16x16x32_bf16(a0, b0, c, 0, 0, 0);
      c = __builtin_amdgcn_mfma_f32_16x16x32_bf16(a1, b1, c, 0, 0, 0);
      for (int r = 0; r < 4; ++r) {
        float p = __expf(c[r] * SCALE - mrow[r]) * lrow[r];
        int row = myrow0 + quad * 4 + r;
        attnp[(long)row * 2048 + kt * 64 + nt * 16 + l16] = p;
        p_s[row][nt * 16 + l16] = f2bf(p);
      }
    }
    __syncthreads();
    short8 pa0 = *(const short8*)&p_s[myrow0 + l16][quad * 8];
    short8 pa1 = *(const short8*)&p_s[myrow0 + l16][32 + quad * 8];
    for (int nt = 0; nt < 4; ++nt) {
      short8 vb0 = *(const short8*)&v_s[nt * 16 + l16][quad * 8];
      short8 vb1 = *(const short8*)&v_s[nt * 16 + l16][32 + quad * 8];
      oacc[nt] = __builtin_amdgcn_mfma_f32_16x16x32_bf16(pa0, vb0, oacc[nt], 0, 0, 0);
      oacc[nt] = __builtin_amdgcn_mfma_f32_16x16x32_bf16(pa1, vb1, oacc[nt], 0, 0, 0);
    }
  }

  for (int nt = 0; nt < 4; ++nt)
    for (int r = 0; r < 4; ++r) {
      int row = myrow0 + quad * 4 + r;
      long l = (long)qb * 64 + row;
      int d = nt * 16 + l16;
      yh_out[((long)b * 2048 + l) * 1024 + h * 64 + d] = oacc[nt][r];
    }
}

extern "C" void kernel_launch(void* const* d_in, const int* in_sizes, int n_in,
                              void* d_out, int out_size, void* d_ws, size_t ws_size,
                              hipStream_t stream) {
  const float* q   = (const float*)d_in[0];
  const float* k   = (const float*)d_in[1];
  const float* v   = (const float*)d_in[2];
  const float* wq  = (const float*)d_in[3];
  const float* wk  = (const float*)d_in[4];
  const float* wv  = (const float*)d_in[5];
  const float* fcy = (const float*)d_in[6];

  float* y_out = (float*)d_out;                      // 2*2048*1024 fp32
  float* attn_out = (float*)d_out + 4194304;         // 2*16*2048*2048 fp32

  char* ws = (char*)d_ws;
  short* qh  = (short*)(ws);                         // 4096*1024 bf16 (b,h,l,d)
  short* kh  = (short*)(ws + 8388608);               // 4096*1024 bf16 (b,h,l,d)
  short* vht = (short*)(ws + 16777216);              // 4096*1024 bf16 (b,h,d,l)
  float* yh  = (float*)(ws + 25165824);              // 4096*1024 fp32 (b,l,h*64+d)

  gemm_bt<0><<<dim3(32, 8, 1), 256, 0, stream>>>(q, wq, qh, 4096, 1024, 1024, 0, 0);
  gemm_bt<0><<<dim3(32, 8, 1), 256, 0, stream>>>(k, wk, kh, 4096, 1024, 1024, 0, 0);
  gemm_bt<1><<<dim3(8, 16, 2), 256, 0, stream>>>(wv, v, vht, 1024, 2048, 1024, 0, 2048L * 1024);
  attn_kernel<<<dim3(32, 16, 2), 256, 0, stream>>>(qh, kh, vht, attn_out, yh);
  gemm_bt<2><<<dim3(32, 8, 1), 256, 0, stream>>>(yh, fcy, y_out, 4096, 1024, 1024, 0, 0);
}